// Round 6
// baseline (344.745 us; speedup 1.0000x reference)
//
#include <hip/hip_runtime.h>
#include <cmath>

// TelephotoInterp: rotate+shift+drift 8.4M particles, CIC-paint z-slab onto
// res x res (2048^2) f32 grid.
//
// Round-12: SIX structural theories falsified (occupancy r7, LDS-chain r8,
// global atomics r9, barrier convoy r10, load coalescing r11) -- tp_bin
// pinned at ~90-104us, all pipes <25%. The one component never varied: the
// LDS staging machinery itself (buf arrays, ds_add_rtn->ds_write dependent
// pair, flush, residue, 32-80KB LDS). This round DELETES it: deposit =
// one block-shared ds_add_rtn + one fire-and-forget 4B global store into a
// deterministic per-(bucket,block) arena row [bucket][block][32]. No buf,
// no flush, no residue drain, 2 barriers total. Scattered dword stores are
// latency-insensitive; their L2 working set is 256 hot rows/block. LDS
// 80KB->1.3KB (occupancy register-bound, ~16 waves/CU at 1008 blocks).
// lambda=16.3 vs SLOTS=32 -> overflow ~1e-4 -> scatter_direct fallback.
// Loads: r10's proven float4 lane-contiguous path (r11 dense regressed).
// Paint: linear coalesced arena scan with u8 counts (unchanged shape).

#define TSZ    128        // paint tile edge (cells)
#define NBKT   256        // buckets (= max tiles^2 in fast path, tiles<=16)
#define SLOTS  32         // arena records per (bucket,block)
#define NTH    256        // block size (4 waves)
#define WPB    4          // waves per block
#define NBLK   1008       // grid (~4 blocks/CU; 8 XCD x 126)
#define NWAVES (NBLK*WPB)
#define VEC    4          // particles per lane per chunk (lane-contiguous)

__device__ __forceinline__ float fast_rcp(float x)  { return __builtin_amdgcn_rcpf(x); }
__device__ __forceinline__ float fast_sqrt(float x) { return __builtin_amdgcn_sqrtf(x); }

__device__ __forceinline__ int wrap_idx(int v, int res) {   // generic (fallback path)
    v += (v < 0) ? res : 0;
    v += (v < 0) ? res : 0;
    v += (v < 0) ? res : 0;
    v -= (v >= res) ? res : 0;
    v -= (v >= res) ? res : 0;
    v -= (v >= res) ? res : 0;
    if (v < 0 || v >= res) { v %= res; if (v < 0) v += res; }  // safety net
    return v;
}

__device__ __forceinline__ void scatter_direct(float* __restrict__ out, int res,
                                               int gx0, int gy0, float fx, float fy) {
    int gx1 = gx0 + 1; if (gx1 >= res) gx1 = 0;
    int gy1 = gy0 + 1; if (gy1 >= res) gy1 = 0;
    atomicAdd(&out[gx0 * res + gy0], (1.0f - fx) * (1.0f - fy));
    atomicAdd(&out[gx1 * res + gy0], fx * (1.0f - fy));
    atomicAdd(&out[gx0 * res + gy1], (1.0f - fx) * fy);
    atomicAdd(&out[gx1 * res + gy1], fx * fy);
}

// rec = lx7<<25 | ly7<<18 | qx9<<9 | qy9
__device__ __forceinline__ void rec_decode(unsigned rec, int b, int tiles,
                                           int& gx, int& gy, float& fx, float& fy) {
    int tx = b / tiles, ty = b - tx * tiles;   // rare path only
    gx = (tx << 7) + (int)(rec >> 25);
    gy = (ty << 7) + (int)((rec >> 18) & 127u);
    fx = (float)((rec >> 9) & 511u) * (1.0f / 512.0f);
    fy = (float)(rec & 511u) * (1.0f / 512.0f);
}

// uniforms for the per-particle fast path
struct Uni {
    float m00, m01, m02, m10, m11, m12, m20, m21, m22;
    float ox, oy, oz, shift;
    float r_lo, r_hi, t, gp_t, scale;
    int   resm1, res, tiles;
    bool  inside;
};

// per-particle result (registers only; callers fully unrolled)
struct PR {
    unsigned rec, st;
    int ix0, iy0;
    float fx, fy;
    bool val;
};

// ---------------- per-particle compute (branch-free, no side effects) ----
__device__ __forceinline__ PR tp_compute(
    const Uni& u, unsigned dummy,
    float px, float py, float pz, float vx, float vy, float vz)
{
    float X, Y, Z;
    if (u.inside) {
        X = px; Y = py; Z = pz;
    } else {
        const float qx_ = px - u.ox, qy_ = py - u.oy, qz_ = pz - u.oz;
        float rx = u.m00 * qx_ + u.m01 * qy_ + u.m02 * qz_;
        float ry = u.m10 * qx_ + u.m11 * qy_ + u.m12 * qz_;
        float rz = u.m20 * qx_ + u.m21 * qy_ + u.m22 * qz_ + u.shift;

        const float vrx = u.m00 * vx + u.m01 * vy + u.m02 * vz;
        const float vry = u.m10 * vx + u.m11 * vy + u.m12 * vz;
        const float vrz = u.m20 * vx + u.m21 * vy + u.m22 * vz;

        const float dx = rx - u.ox, dy = ry - u.oy, dz = rz - u.oz;
        const float dist  = fast_sqrt(dx * dx + dy * dy + dz * dz);
        const float a_tgt = fast_rcp(1.0f + dist * (1.0f / 3000.0f));
        const float ac    = fast_sqrt(u.t * a_tgt);
        const float gp_a  = a_tgt * fast_sqrt(a_tgt);          // a^1.5
        const float drift = (gp_a - u.gp_t) * fast_rcp(1.5f * fast_sqrt(ac));

        X = rx + drift * vrx + u.ox;
        Y = ry + drift * vry + u.oy;
        Z = rz + drift * vrz + u.oz;
    }
    PR o;
    o.val = (Z >= u.r_lo && Z < u.r_hi);

    // all of the below is finite/safe even for rejected particles
    const float gx = X * u.scale, gy = Y * u.scale;
    const float fgx = floorf(gx), fgy = floorf(gy);
    o.fx = gx - fgx; o.fy = gy - fgy;
    o.ix0 = ((int)fgx) & u.resm1;   // exact mod for pow2 res
    o.iy0 = ((int)fgy) & u.resm1;
    const unsigned st = (unsigned)((o.ix0 >> 7) * u.tiles + (o.iy0 >> 7));
    o.st = o.val ? st : dummy;      // invalid lanes -> per-lane dummy bucket

    unsigned qx = (unsigned)(o.fx * 512.0f + 0.5f); if (qx > 511u) qx = 511u;
    unsigned qy = (unsigned)(o.fy * 512.0f + 0.5f); if (qy > 511u) qy = 511u;
    o.rec = ((unsigned)(o.ix0 & 127) << 25) | ((unsigned)(o.iy0 & 127) << 18)
          | (qx << 9) | qy;
    return o;
}

// ---------------- K1: transform + minimal bin (1 LDS atomic + 1 store) ----
__global__ __launch_bounds__(NTH) void tp_bin(
    const float* __restrict__ pos, const float* __restrict__ vel,
    const float* __restrict__ rotations, const float* __restrict__ observer,
    const float* __restrict__ r_centers, const float* __restrict__ widths,
    const float* __restrict__ t_p, const float* __restrict__ maxd_p,
    const float* __restrict__ box_p, const int* __restrict__ shell_p,
    const int* __restrict__ ridx_p,
    unsigned char* __restrict__ cnts, unsigned* __restrict__ grec,
    float* __restrict__ out, int res, int tiles, int n, int cpw)
{
    __shared__ unsigned fill[NBKT + 64];   // +64 per-lane dummy buckets

    const int tid  = threadIdx.x;
    const int wv   = tid >> 6;
    const int lane = tid & 63;

    for (int b = tid; b < NBKT + 64; b += NTH) fill[b] = 0;

    Uni u;
    {
        const int   shell    = shell_p[0];
        const float r_center = r_centers[shell];
        const float width    = widths[shell];
        const float maxd     = maxd_p[0];
        const float box      = box_p[0];
        u.t      = t_p[0];
        u.inside = (r_center + width * 0.5f) <= maxd;
        int ridx = ridx_p[0] % 47; if (ridx < 0) ridx += 47;
        const float* M = rotations + 9 * ridx;
        u.m00 = M[0]; u.m01 = M[1]; u.m02 = M[2];
        u.m10 = M[3]; u.m11 = M[4]; u.m12 = M[5];
        u.m20 = M[6]; u.m21 = M[7]; u.m22 = M[8];
        u.ox = observer[0]; u.oy = observer[1]; u.oz = observer[2];
        u.shift = floorf(r_center / maxd) * maxd;
        u.r_lo = r_center - width * 0.5f;
        u.r_hi = r_center + width * 0.5f;
        u.gp_t = u.t * sqrtf(u.t);
        u.scale = (float)res / box;
        u.resm1 = res - 1; u.res = res; u.tiles = tiles;
    }

    __syncthreads();

    const unsigned w = (unsigned)(blockIdx.x * WPB + wv);
    const unsigned dummy = (unsigned)(NBKT + lane);
    const float4* __restrict__ pos4 = (const float4*)pos;
    const float4* __restrict__ vel4 = (const float4*)vel;

    for (int k = 0; k < cpw; ++k) {
        const int base = (((k * NWAVES + (int)w) * 64) + lane) * VEC;
        PR pr[4];
        if (base + VEC <= n) {
            const int q = base * 3 / 4;   // float4 index (base*3 divisible by 4)
            const float4 a = pos4[q], b = pos4[q + 1], c = pos4[q + 2];
            if (u.inside) {
                pr[0] = tp_compute(u, dummy, a.x, a.y, a.z, 0, 0, 0);
                pr[1] = tp_compute(u, dummy, a.w, b.x, b.y, 0, 0, 0);
                pr[2] = tp_compute(u, dummy, b.z, b.w, c.x, 0, 0, 0);
                pr[3] = tp_compute(u, dummy, c.y, c.z, c.w, 0, 0, 0);
            } else {
                const float4 d = vel4[q], e = vel4[q + 1], f = vel4[q + 2];
                pr[0] = tp_compute(u, dummy, a.x, a.y, a.z, d.x, d.y, d.z);
                pr[1] = tp_compute(u, dummy, a.w, b.x, b.y, d.w, e.x, e.y);
                pr[2] = tp_compute(u, dummy, b.z, b.w, c.x, e.z, e.w, f.x);
                pr[3] = tp_compute(u, dummy, c.y, c.z, c.w, f.y, f.z, f.w);
            }
        } else {
            #pragma unroll
            for (int j = 0; j < VEC; ++j) {
                const int i = base + j;
                const bool ok = (i >= 0) && (i < n);
                float px = 0, py = 0, pz = 0, vx = 0, vy = 0, vz = 0;
                if (ok) {
                    px = pos[3 * i]; py = pos[3 * i + 1]; pz = pos[3 * i + 2];
                    if (!u.inside) {
                        vx = vel[3 * i]; vy = vel[3 * i + 1]; vz = vel[3 * i + 2];
                    }
                }
                PR t = tp_compute(u, dummy, px, py, pz, vx, vy, vz);
                if (!ok) { t.val = false; t.st = dummy; }
                pr[j] = t;
            }
        }
        // deposit: 4 back-to-back LDS atomics, then fire-and-forget stores
        unsigned pp[4];
        #pragma unroll
        for (int j = 0; j < 4; ++j) pp[j] = atomicAdd(&fill[pr[j].st], 1u);
        #pragma unroll
        for (int j = 0; j < 4; ++j) {
            if (pr[j].val) {
                if (pp[j] < SLOTS)
                    grec[((size_t)pr[j].st * NBLK + blockIdx.x) * SLOTS + pp[j]] = pr[j].rec;
                else
                    scatter_direct(out, u.res, pr[j].ix0, pr[j].iy0, pr[j].fx, pr[j].fy);
            }
        }
    }

    __syncthreads();
    if (tid < NBKT) {
        unsigned c = fill[tid];
        if (c > SLOTS) c = SLOTS;
        cnts[(size_t)blockIdx.x * NBKT + tid] = (unsigned char)c;
    }
}

// ---------------- K2: paint (one 128-tile per block, quad u64 accumulate) ----
// 4 parity-staggered quad grids; a record at (li,lj) hits exactly one quad:
// grid (li&1, lj&1), index (li>>1, lj>>1). u64 = 4x u16 fixed-point (2^-10):
// slot(r,s) at bits 16*(r*2+s) = weight for cell (li+r, lj+s). Exact while
// each cell's weight-sum < 64 (actual max ~12).
// Record read: linear coalesced scan of this bucket's NBLK*SLOTS arena
// region; slot validity via per-block u8 counts preloaded in LDS.
__global__ __launch_bounds__(1024) void tp_paint(
    const unsigned char* __restrict__ cnts, const unsigned* __restrict__ grec,
    float* __restrict__ out, int res, int tiles)
{
    __shared__ unsigned long long quad[4][64 * 64];   // 128 KB
    __shared__ unsigned char cs[NBLK];                // per-source-block counts
    const int b = blockIdx.x;
    const int tx = b / tiles, ty = b - tx * tiles;

    for (int c = threadIdx.x; c < 4 * 64 * 64; c += blockDim.x)
        quad[c >> 12][c & 4095] = 0ull;
    for (int i = threadIdx.x; i < NBLK; i += blockDim.x)
        cs[i] = cnts[(size_t)i * NBKT + b];
    __syncthreads();

    const unsigned* __restrict__ rr = grec + (size_t)b * NBLK * SLOTS;
    const int total = NBLK * SLOTS;
    for (int idx = threadIdx.x; idx < total; idx += blockDim.x) {
        const unsigned p = rr[idx];                    // coalesced stream
        if ((idx & (SLOTS - 1)) < (int)cs[idx >> 5]) { // SLOTS == 32
            const int li = (int)(p >> 25);
            const int lj = (int)((p >> 18) & 127u);
            const unsigned qx = (p >> 9) & 511u;
            const unsigned qy = p & 511u;
            const unsigned ax = 512u - qx, ay = 512u - qy;
            const unsigned long long w00 = (ax * ay + 128u) >> 8;
            const unsigned long long w01 = (ax * qy + 128u) >> 8;
            const unsigned long long w10 = (qx * ay + 128u) >> 8;
            const unsigned long long w11 = (qx * qy + 128u) >> 8;
            const unsigned long long pk = w00 | (w01 << 16) | (w10 << 32) | (w11 << 48);
            const int g = ((li & 1) << 1) | (lj & 1);
            atomicAdd(&quad[g][(li >> 1) * 64 + (lj >> 1)], pk);
        }
    }
    __syncthreads();

    for (int c = threadIdx.x; c < (TSZ + 1) * (TSZ + 1); c += blockDim.x) {
        const int i = c / (TSZ + 1), j = c - i * (TSZ + 1);
        unsigned acc = 0;
        #pragma unroll
        for (int r = 0; r < 2; ++r) {
            const int ii = i - r;
            if (ii < 0 || ii > TSZ - 1) continue;
            #pragma unroll
            for (int s = 0; s < 2; ++s) {
                const int jj = j - s;
                if (jj < 0 || jj > TSZ - 1) continue;
                const int g = ((ii & 1) << 1) | (jj & 1);
                const unsigned long long v = quad[g][(ii >> 1) * 64 + (jj >> 1)];
                acc += (unsigned)((v >> (16 * (r * 2 + s))) & 0xffffull);
            }
        }
        const float val = (float)acc * (1.0f / 1024.0f);
        int gx = tx * TSZ + i; if (gx >= res) gx -= res;
        int gy = ty * TSZ + j; if (gy >= res) gy -= res;
        float* dst = &out[gx * res + gy];
        if (i == 0 || j == 0 || i == TSZ || j == TSZ) {
            if (val != 0.0f) atomicAdd(dst, val);   // halo-shared frame cells
        } else {
            *dst += val;   // exclusive writer; += keeps fallback atomics
        }
    }
}

// ---------------- fallback direct kernel (non-pow2 / odd res / small ws) ----
__global__ __launch_bounds__(256) void tp_direct(
    const float* __restrict__ pos, const float* __restrict__ vel,
    const float* __restrict__ rotations, const float* __restrict__ observer,
    const float* __restrict__ r_centers, const float* __restrict__ widths,
    const float* __restrict__ t_p, const float* __restrict__ maxd_p,
    const float* __restrict__ box_p, const int* __restrict__ shell_p,
    const int* __restrict__ ridx_p, float* __restrict__ out, int res, int n)
{
    int i = blockIdx.x * blockDim.x + threadIdx.x;
    if (i >= n) return;
    const int   shell    = shell_p[0];
    const float r_center = r_centers[shell];
    const float width    = widths[shell];
    const float maxd     = maxd_p[0];
    const float box      = box_p[0];
    const float t        = t_p[0];
    const bool  inside   = (r_center + width * 0.5f) <= maxd;
    int ridx = ridx_p[0] % 47; if (ridx < 0) ridx += 47;

    float px = pos[3 * i], py = pos[3 * i + 1], pz = pos[3 * i + 2];
    float X, Y, Z;
    if (inside) {
        X = px; Y = py; Z = pz;
    } else {
        const float* M = rotations + 9 * ridx;
        const float ox = observer[0], oy = observer[1], oz = observer[2];
        const float qx = px - ox, qy = py - oy, qz = pz - oz;
        float rx = M[0] * qx + M[1] * qy + M[2] * qz;
        float ry = M[3] * qx + M[4] * qy + M[5] * qz;
        float rz = M[6] * qx + M[7] * qy + M[8] * qz + floorf(r_center / maxd) * maxd;
        const float vx = vel[3 * i], vy = vel[3 * i + 1], vz = vel[3 * i + 2];
        const float vrx = M[0] * vx + M[1] * vy + M[2] * vz;
        const float vry = M[3] * vx + M[4] * vy + M[5] * vz;
        const float vrz = M[6] * vx + M[7] * vy + M[8] * vz;
        const float dx = rx - ox, dy = ry - oy, dz = rz - oz;
        const float dist  = sqrtf(dx * dx + dy * dy + dz * dz);
        const float a_tgt = 1.0f / (1.0f + dist / 3000.0f);
        const float ac    = sqrtf(t * a_tgt);
        const float drift = (a_tgt * sqrtf(a_tgt) - t * sqrtf(t)) / (1.5f * sqrtf(ac));
        X = rx + drift * vrx + ox;
        Y = ry + drift * vry + oy;
        Z = rz + drift * vrz + oz;
    }
    if (!(Z >= r_center - width * 0.5f && Z < r_center + width * 0.5f)) return;

    const float scale = (float)res / box;
    const float gx = X * scale, gy = Y * scale;
    const float fgx = floorf(gx), fgy = floorf(gy);
    scatter_direct(out, res, wrap_idx((int)fgx, res), wrap_idx((int)fgy, res),
                   gx - fgx, gy - fgy);
}

extern "C" void kernel_launch(void* const* d_in, const int* in_sizes, int n_in,
                              void* d_out, int out_size, void* d_ws, size_t ws_size,
                              hipStream_t stream) {
    const float* pos   = (const float*)d_in[0];
    const float* velv  = (const float*)d_in[1];
    const float* rot   = (const float*)d_in[2];
    const float* obs   = (const float*)d_in[3];
    const float* rc    = (const float*)d_in[4];
    const float* dw    = (const float*)d_in[5];
    const float* t     = (const float*)d_in[6];
    const float* maxd  = (const float*)d_in[7];
    const float* box   = (const float*)d_in[8];
    const int*   shell = (const int*)d_in[9];
    const int*   ridx  = (const int*)d_in[10];
    float* out = (float*)d_out;

    const int n   = in_sizes[0] / 3;
    const int res = (int)llround(sqrt((double)out_size));

    // output is poisoned with 0xAA before every timed launch — zero it.
    hipMemsetAsync(out, 0, (size_t)out_size * sizeof(float), stream);

    const int tiles = res / TSZ;
    const int nt2 = tiles * tiles;
    const size_t rec_bytes = (size_t)NBKT * NBLK * SLOTS * sizeof(unsigned);
    const size_t cnt_bytes = (size_t)NBLK * NBKT;   // u8 counts
    const bool pow2 = res > 0 && (res & (res - 1)) == 0;

    if (!pow2 || res % TSZ != 0 || nt2 > NBKT ||
        (long long)res * res != (long long)out_size ||
        ws_size < rec_bytes + cnt_bytes) {
        tp_direct<<<(n + 255) / 256, 256, 0, stream>>>(
            pos, velv, rot, obs, rc, dw, t, maxd, box, shell, ridx, out, res, n);
        return;
    }

    unsigned* grec = (unsigned*)d_ws;
    unsigned char* cnts = (unsigned char*)d_ws + rec_bytes;

    const int per_sweep = NWAVES * 64 * VEC;             // particles per chunk sweep
    const int cpw = (n + per_sweep - 1) / per_sweep;     // chunks per wave
    tp_bin<<<NBLK, NTH, 0, stream>>>(
        pos, velv, rot, obs, rc, dw, t, maxd, box, shell, ridx,
        cnts, grec, out, res, tiles, n, cpw);

    tp_paint<<<nt2, 1024, 0, stream>>>(cnts, grec, out, res, tiles);
}

// Round 7
// 283.803 us; speedup vs baseline: 1.2147x; 1.2147x over previous
//
#include <hip/hip_runtime.h>
#include <cmath>

// TelephotoInterp: rotate+shift+drift 8.4M particles, CIC-paint z-slab onto
// res x res (2048^2) f32 grid.
//
// Round-13: REVERT to round-0 (best measured, 281.7us) + nontemporal input
// loads. Seven structural variants (r7-r12: occupancy, LDS-chain ILP, zero
// global atomics, zero barriers, dense loads, no LDS staging) all obeyed
// ONE law: tp_bin dur = HBM_bytes / 1.33 TB/s (r12's +54MB write -> +45us
// at 1.2TB/s marginal proved it). tp_bin is memory-slice-bound; the only
// lever is fewer HBM bytes / better L3 residency. Inputs (201MB) are read
// once per iteration: nt loads stop them from evicting the arena (33.5MB)
// and out (16.8MB) from L3, making tp_paint's arena reads L3-hits.
// Everything else is round-0 verbatim (LDS-batched bin, parity-staggered
// quad u64 paint).

#define TSZ    128        // paint tile edge (cells)
#define NBKT   256        // K1 buckets (= max tiles^2 in fast path, tiles<=16)
#define NXCC   8
#define CAP    4096       // records per (xcc,bucket) segment (mean ~2050)
#define DEPTH  32         // LDS slots per bucket
#define NTH    256        // K1 block size
#define NBLK   1024       // K1 grid (4 blocks/CU, persistent)
#define VEC    4          // particles per thread per round
#define DESCMAX 512       // sum floor(c/16) <= NBKT*DEPTH/16 = 512

typedef float vf4 __attribute__((ext_vector_type(4)));

__device__ __forceinline__ int get_xcc_id() {
    // s_getreg_b32 hwreg(HW_REG_XCC_ID=20, offset=0, size=4)  [learn_hip m09]
    int x = __builtin_amdgcn_s_getreg((3 << 11) | (0 << 6) | 20);
    return x & (NXCC - 1);   // any value in [0,8) is CORRECT; only perf differs
}

__device__ __forceinline__ float fast_rcp(float x)  { return __builtin_amdgcn_rcpf(x); }
__device__ __forceinline__ float fast_sqrt(float x) { return __builtin_amdgcn_sqrtf(x); }

__device__ __forceinline__ int wrap_idx(int v, int res) {   // generic (fallback path)
    v += (v < 0) ? res : 0;
    v += (v < 0) ? res : 0;
    v += (v < 0) ? res : 0;
    v -= (v >= res) ? res : 0;
    v -= (v >= res) ? res : 0;
    v -= (v >= res) ? res : 0;
    if (v < 0 || v >= res) { v %= res; if (v < 0) v += res; }  // safety net
    return v;
}

__device__ __forceinline__ void scatter_direct(float* __restrict__ out, int res,
                                               int gx0, int gy0, float fx, float fy) {
    int gx1 = gx0 + 1; if (gx1 >= res) gx1 = 0;
    int gy1 = gy0 + 1; if (gy1 >= res) gy1 = 0;
    atomicAdd(&out[gx0 * res + gy0], (1.0f - fx) * (1.0f - fy));
    atomicAdd(&out[gx1 * res + gy0], fx * (1.0f - fy));
    atomicAdd(&out[gx0 * res + gy1], (1.0f - fx) * fy);
    atomicAdd(&out[gx1 * res + gy1], fx * fy);
}

// rec = lx7<<25 | ly7<<18 | qx9<<9 | qy9
__device__ __forceinline__ void rec_decode(unsigned rec, int b, int tiles,
                                           int& gx, int& gy, float& fx, float& fy) {
    int tx = b / tiles, ty = b - tx * tiles;   // rare path only
    gx = (tx << 7) + (int)(rec >> 25);
    gy = (ty << 7) + (int)((rec >> 18) & 127u);
    fx = (float)((rec >> 9) & 511u) * (1.0f / 512.0f);
    fy = (float)(rec & 511u) * (1.0f / 512.0f);
}

// uniforms for the per-particle fast path
struct Uni {
    float m00, m01, m02, m10, m11, m12, m20, m21, m22;
    float ox, oy, oz, shift;
    float r_lo, r_hi, t, gp_t, scale;
    int   resm1, res, tiles;
    bool  inside;
};

// ---------------- K1 per-particle fast path ----------------
__device__ __forceinline__ void tp_process(
    const Uni& u, float px, float py, float pz, float vx, float vy, float vz,
    unsigned* __restrict__ fill, unsigned* __restrict__ buf,
    float* __restrict__ out)
{
    float X, Y, Z;
    if (u.inside) {
        X = px; Y = py; Z = pz;
    } else {
        const float qx_ = px - u.ox, qy_ = py - u.oy, qz_ = pz - u.oz;
        float rx = u.m00 * qx_ + u.m01 * qy_ + u.m02 * qz_;
        float ry = u.m10 * qx_ + u.m11 * qy_ + u.m12 * qz_;
        float rz = u.m20 * qx_ + u.m21 * qy_ + u.m22 * qz_ + u.shift;

        const float vrx = u.m00 * vx + u.m01 * vy + u.m02 * vz;
        const float vry = u.m10 * vx + u.m11 * vy + u.m12 * vz;
        const float vrz = u.m20 * vx + u.m21 * vy + u.m22 * vz;

        const float dx = rx - u.ox, dy = ry - u.oy, dz = rz - u.oz;
        const float dist  = fast_sqrt(dx * dx + dy * dy + dz * dz);
        const float a_tgt = fast_rcp(1.0f + dist * (1.0f / 3000.0f));
        const float ac    = fast_sqrt(u.t * a_tgt);
        const float gp_a  = a_tgt * fast_sqrt(a_tgt);          // a^1.5
        const float drift = (gp_a - u.gp_t) * fast_rcp(1.5f * fast_sqrt(ac));

        X = rx + drift * vrx + u.ox;
        Y = ry + drift * vry + u.oy;
        Z = rz + drift * vrz + u.oz;
    }
    if (!(Z >= u.r_lo && Z < u.r_hi)) return;

    const float gx = X * u.scale, gy = Y * u.scale;
    const float fgx = floorf(gx), fgy = floorf(gy);
    const float fx = gx - fgx, fy = gy - fgy;
    const int ix0 = ((int)fgx) & u.resm1;   // exact mod for pow2 res
    const int iy0 = ((int)fgy) & u.resm1;
    const int st = (ix0 >> 7) * u.tiles + (iy0 >> 7);

    unsigned qx = (unsigned)(fx * 512.0f + 0.5f); if (qx > 511u) qx = 511u;
    unsigned qy = (unsigned)(fy * 512.0f + 0.5f); if (qy > 511u) qy = 511u;
    const unsigned rec = ((unsigned)(ix0 & 127) << 25) | ((unsigned)(iy0 & 127) << 18)
                       | (qx << 9) | qy;

    unsigned p = atomicAdd(&fill[st], 1u);
    if (p < DEPTH) buf[st * DEPTH + p] = rec;
    else { atomicSub(&fill[st], 1u); scatter_direct(out, u.res, ix0, iy0, fx, fy); }
}

// ---------------- K1: transform + LDS-batched bin ----------------
__global__ __launch_bounds__(NTH) void tp_bin(
    const float* __restrict__ pos, const float* __restrict__ vel,
    const float* __restrict__ rotations, const float* __restrict__ observer,
    const float* __restrict__ r_centers, const float* __restrict__ widths,
    const float* __restrict__ t_p, const float* __restrict__ maxd_p,
    const float* __restrict__ box_p, const int* __restrict__ shell_p,
    const int* __restrict__ ridx_p,
    unsigned* __restrict__ gcnt, unsigned* __restrict__ grec,
    float* __restrict__ out, int res, int tiles, int n, int rounds)
{
    __shared__ unsigned fill[NBKT];
    __shared__ unsigned buf[NBKT * DEPTH];
    __shared__ unsigned descB[DESCMAX];
    __shared__ unsigned descD[DESCMAX];
    __shared__ unsigned ndesc;

    const int tid = threadIdx.x;
    for (int b = tid; b < NBKT; b += NTH) fill[b] = 0;
    if (tid == 0) ndesc = 0;

    Uni u;
    {
        const int   shell    = shell_p[0];
        const float r_center = r_centers[shell];
        const float width    = widths[shell];
        const float maxd     = maxd_p[0];
        const float box      = box_p[0];
        u.t      = t_p[0];
        u.inside = (r_center + width * 0.5f) <= maxd;
        int ridx = ridx_p[0] % 47; if (ridx < 0) ridx += 47;
        const float* M = rotations + 9 * ridx;
        u.m00 = M[0]; u.m01 = M[1]; u.m02 = M[2];
        u.m10 = M[3]; u.m11 = M[4]; u.m12 = M[5];
        u.m20 = M[6]; u.m21 = M[7]; u.m22 = M[8];
        u.ox = observer[0]; u.oy = observer[1]; u.oz = observer[2];
        u.shift = floorf(r_center / maxd) * maxd;
        u.r_lo = r_center - width * 0.5f;
        u.r_hi = r_center + width * 0.5f;
        u.gp_t = u.t * sqrtf(u.t);
        u.scale = (float)res / box;
        u.resm1 = res - 1; u.res = res; u.tiles = tiles;
    }

    const int xcc = get_xcc_id();
    const int segbase = xcc * NBKT;
    const vf4* __restrict__ pos4 = (const vf4*)pos;
    const vf4* __restrict__ vel4 = (const vf4*)vel;

    __syncthreads();

    for (int r = 0; r < rounds; ++r) {
        const int base = ((r * NBLK + blockIdx.x) * NTH + tid) * VEC;
        // phase 1: transform + deposit (4 particles via 3+3 float4 nt-loads)
        if (base + VEC <= n) {
            const int q = base * 3 / 4;   // float4 index (base*3 divisible by 4)
            const vf4 a = __builtin_nontemporal_load(pos4 + q);
            const vf4 b = __builtin_nontemporal_load(pos4 + q + 1);
            const vf4 c = __builtin_nontemporal_load(pos4 + q + 2);
            if (u.inside) {
                tp_process(u, a.x, a.y, a.z, 0, 0, 0, fill, buf, out);
                tp_process(u, a.w, b.x, b.y, 0, 0, 0, fill, buf, out);
                tp_process(u, b.z, b.w, c.x, 0, 0, 0, fill, buf, out);
                tp_process(u, c.y, c.z, c.w, 0, 0, 0, fill, buf, out);
            } else {
                const vf4 d = __builtin_nontemporal_load(vel4 + q);
                const vf4 e = __builtin_nontemporal_load(vel4 + q + 1);
                const vf4 f = __builtin_nontemporal_load(vel4 + q + 2);
                tp_process(u, a.x, a.y, a.z, d.x, d.y, d.z, fill, buf, out);
                tp_process(u, a.w, b.x, b.y, d.w, e.x, e.y, fill, buf, out);
                tp_process(u, b.z, b.w, c.x, e.z, e.w, f.x, fill, buf, out);
                tp_process(u, c.y, c.z, c.w, f.y, f.z, f.w, fill, buf, out);
            }
        } else {
            for (int p = 0; p < VEC; ++p) {
                const int i = base + p;
                if (i < n)
                    tp_process(u, pos[3 * i], pos[3 * i + 1], pos[3 * i + 2],
                               vel[3 * i], vel[3 * i + 1], vel[3 * i + 2],
                               fill, buf, out);
            }
        }
        __syncthreads();
        // phase 2a: build flush descriptors (thread b <-> bucket b)
        if (tid < NBKT) {
            const unsigned c = fill[tid];
            const unsigned k = c >> 4;
            if (k) {
                unsigned gbase = atomicAdd(&gcnt[segbase + tid], 16u * k);
                unsigned d = atomicAdd(&ndesc, k);
                for (unsigned g = 0; g < k; ++g) {
                    descB[d + g] = (unsigned)tid | ((g * 16u) << 16);
                    descD[d + g] = gbase + 16u * g;
                }
            }
        }
        __syncthreads();
        // phase 2b: cooperative coalesced flush, 16 lanes per descriptor
        const unsigned nd = ndesc;
        for (unsigned did = (unsigned)(tid >> 4); did < nd; did += NTH / 16) {
            const unsigned e = descB[did];
            const unsigned b = e & 0xffffu, so = e >> 16;
            const unsigned dst = descD[did] + (unsigned)(tid & 15);
            const unsigned rv = buf[b * DEPTH + so + (tid & 15)];
            if (dst < CAP) {
                grec[(size_t)(segbase + b) * CAP + dst] = rv;
            } else {  // segment overflow: correct fallback
                int gx0, gy0; float ffx, ffy;
                rec_decode(rv, (int)b, u.tiles, gx0, gy0, ffx, ffy);
                scatter_direct(out, u.res, gx0, gy0, ffx, ffy);
            }
        }
        __syncthreads();
        // phase 2c: compact residues, reset descriptor count
        if (tid < NBKT) {
            const unsigned c = fill[tid];
            const unsigned k = c >> 4;
            if (k) {
                const unsigned resid = c - 16u * k;
                for (unsigned j = 0; j < resid; ++j)
                    buf[tid * DEPTH + j] = buf[tid * DEPTH + 16u * k + j];
                fill[tid] = resid;
            }
        }
        if (tid == 0) ndesc = 0;
        __syncthreads();
    }

    // final flush: drain residues (c <= 15 each)
    if (tid < NBKT) {
        const unsigned c = fill[tid];
        if (c) {
            unsigned d = atomicAdd(&ndesc, 1u);
            unsigned gbase = atomicAdd(&gcnt[segbase + tid], c);
            descB[d] = (unsigned)tid | (c << 16);
            descD[d] = gbase;
        }
    }
    __syncthreads();
    const unsigned nd = ndesc;
    for (unsigned did = (unsigned)(tid >> 4); did < nd; did += NTH / 16) {
        const unsigned e = descB[did];
        const unsigned b = e & 0xffffu, c = e >> 16;
        const unsigned lane = (unsigned)(tid & 15);
        if (lane < c) {
            const unsigned dst = descD[did] + lane;
            const unsigned rv = buf[b * DEPTH + lane];
            if (dst < CAP) {
                grec[(size_t)(segbase + b) * CAP + dst] = rv;
            } else {
                int gx0, gy0; float ffx, ffy;
                rec_decode(rv, (int)b, u.tiles, gx0, gy0, ffx, ffy);
                scatter_direct(out, u.res, gx0, gy0, ffx, ffy);
            }
        }
    }
}

// ---------------- K2: paint (one 128-tile per block, quad u64 accumulate) ----
// 4 parity-staggered quad grids; a record at (li,lj) hits exactly one quad:
// grid (li&1, lj&1), index (li>>1, lj>>1). u64 = 4x u16 fixed-point (2^-10):
// slot(r,s) at bits 16*(r*2+s) = weight for cell (li+r, lj+s). Exact while
// each cell's weight-sum < 64 (actual max ~12).
__global__ __launch_bounds__(1024) void tp_paint(
    const unsigned* __restrict__ gcnt, const unsigned* __restrict__ grec,
    float* __restrict__ out, int res, int tiles)
{
    __shared__ unsigned long long quad[4][64 * 64];   // 128 KB
    const int b = blockIdx.x;
    const int tx = b / tiles, ty = b - tx * tiles;

    for (int c = threadIdx.x; c < 4 * 64 * 64; c += blockDim.x)
        quad[c >> 12][c & 4095] = 0ull;
    __syncthreads();

    for (int x = 0; x < NXCC; ++x) {
        unsigned m = gcnt[x * NBKT + b]; if (m > CAP) m = CAP;
        const unsigned* rr = grec + (size_t)(x * NBKT + b) * CAP;
        for (unsigned k = threadIdx.x; k < m; k += blockDim.x) {
            const unsigned p = rr[k];
            const int li = (int)(p >> 25);
            const int lj = (int)((p >> 18) & 127u);
            const unsigned qx = (p >> 9) & 511u;
            const unsigned qy = p & 511u;
            const unsigned ax = 512u - qx, ay = 512u - qy;
            const unsigned long long w00 = (ax * ay + 128u) >> 8;
            const unsigned long long w01 = (ax * qy + 128u) >> 8;
            const unsigned long long w10 = (qx * ay + 128u) >> 8;
            const unsigned long long w11 = (qx * qy + 128u) >> 8;
            const unsigned long long pk = w00 | (w01 << 16) | (w10 << 32) | (w11 << 48);
            const int g = ((li & 1) << 1) | (lj & 1);
            atomicAdd(&quad[g][(li >> 1) * 64 + (lj >> 1)], pk);
        }
    }
    __syncthreads();

    for (int c = threadIdx.x; c < (TSZ + 1) * (TSZ + 1); c += blockDim.x) {
        const int i = c / (TSZ + 1), j = c - i * (TSZ + 1);
        unsigned acc = 0;
        #pragma unroll
        for (int r = 0; r < 2; ++r) {
            const int ii = i - r;
            if (ii < 0 || ii > TSZ - 1) continue;
            #pragma unroll
            for (int s = 0; s < 2; ++s) {
                const int jj = j - s;
                if (jj < 0 || jj > TSZ - 1) continue;
                const int g = ((ii & 1) << 1) | (jj & 1);
                const unsigned long long v = quad[g][(ii >> 1) * 64 + (jj >> 1)];
                acc += (unsigned)((v >> (16 * (r * 2 + s))) & 0xffffull);
            }
        }
        const float val = (float)acc * (1.0f / 1024.0f);
        int gx = tx * TSZ + i; if (gx >= res) gx -= res;
        int gy = ty * TSZ + j; if (gy >= res) gy -= res;
        float* dst = &out[gx * res + gy];
        if (i == 0 || j == 0 || i == TSZ || j == TSZ) {
            if (val != 0.0f) atomicAdd(dst, val);   // halo-shared frame cells
        } else {
            *dst += val;   // exclusive writer; += keeps fallback atomics
        }
    }
}

// ---------------- fallback direct kernel (non-pow2 / odd res / small ws) ----
__global__ __launch_bounds__(256) void tp_direct(
    const float* __restrict__ pos, const float* __restrict__ vel,
    const float* __restrict__ rotations, const float* __restrict__ observer,
    const float* __restrict__ r_centers, const float* __restrict__ widths,
    const float* __restrict__ t_p, const float* __restrict__ maxd_p,
    const float* __restrict__ box_p, const int* __restrict__ shell_p,
    const int* __restrict__ ridx_p, float* __restrict__ out, int res, int n)
{
    int i = blockIdx.x * blockDim.x + threadIdx.x;
    if (i >= n) return;
    const int   shell    = shell_p[0];
    const float r_center = r_centers[shell];
    const float width    = widths[shell];
    const float maxd     = maxd_p[0];
    const float box      = box_p[0];
    const float t        = t_p[0];
    const bool  inside   = (r_center + width * 0.5f) <= maxd;
    int ridx = ridx_p[0] % 47; if (ridx < 0) ridx += 47;

    float px = pos[3 * i], py = pos[3 * i + 1], pz = pos[3 * i + 2];
    float X, Y, Z;
    if (inside) {
        X = px; Y = py; Z = pz;
    } else {
        const float* M = rotations + 9 * ridx;
        const float ox = observer[0], oy = observer[1], oz = observer[2];
        const float qx = px - ox, qy = py - oy, qz = pz - oz;
        float rx = M[0] * qx + M[1] * qy + M[2] * qz;
        float ry = M[3] * qx + M[4] * qy + M[5] * qz;
        float rz = M[6] * qx + M[7] * qy + M[8] * qz + floorf(r_center / maxd) * maxd;
        const float vx = vel[3 * i], vy = vel[3 * i + 1], vz = vel[3 * i + 2];
        const float vrx = M[0] * vx + M[1] * vy + M[2] * vz;
        const float vry = M[3] * vx + M[4] * vy + M[5] * vz;
        const float vrz = M[6] * vx + M[7] * vy + M[8] * vz;
        const float dx = rx - ox, dy = ry - oy, dz = rz - oz;
        const float dist  = sqrtf(dx * dx + dy * dy + dz * dz);
        const float a_tgt = 1.0f / (1.0f + dist / 3000.0f);
        const float ac    = sqrtf(t * a_tgt);
        const float drift = (a_tgt * sqrtf(a_tgt) - t * sqrtf(t)) / (1.5f * sqrtf(ac));
        X = rx + drift * vrx + ox;
        Y = ry + drift * vry + oy;
        Z = rz + drift * vrz + oz;
    }
    if (!(Z >= r_center - width * 0.5f && Z < r_center + width * 0.5f)) return;

    const float scale = (float)res / box;
    const float gx = X * scale, gy = Y * scale;
    const float fgx = floorf(gx), fgy = floorf(gy);
    scatter_direct(out, res, wrap_idx((int)fgx, res), wrap_idx((int)fgy, res),
                   gx - fgx, gy - fgy);
}

extern "C" void kernel_launch(void* const* d_in, const int* in_sizes, int n_in,
                              void* d_out, int out_size, void* d_ws, size_t ws_size,
                              hipStream_t stream) {
    const float* pos   = (const float*)d_in[0];
    const float* velv  = (const float*)d_in[1];
    const float* rot   = (const float*)d_in[2];
    const float* obs   = (const float*)d_in[3];
    const float* rc    = (const float*)d_in[4];
    const float* dw    = (const float*)d_in[5];
    const float* t     = (const float*)d_in[6];
    const float* maxd  = (const float*)d_in[7];
    const float* box   = (const float*)d_in[8];
    const int*   shell = (const int*)d_in[9];
    const int*   ridx  = (const int*)d_in[10];
    float* out = (float*)d_out;

    const int n   = in_sizes[0] / 3;
    const int res = (int)llround(sqrt((double)out_size));

    // output is poisoned with 0xAA before every timed launch — zero it.
    hipMemsetAsync(out, 0, (size_t)out_size * sizeof(float), stream);

    const int tiles = res / TSZ;
    const int nt2 = tiles * tiles;
    const size_t cnt_bytes = (size_t)NXCC * NBKT * sizeof(unsigned);
    const size_t rec_bytes = (size_t)NXCC * NBKT * CAP * sizeof(unsigned);
    const bool pow2 = res > 0 && (res & (res - 1)) == 0;

    if (!pow2 || res % TSZ != 0 || nt2 > NBKT ||
        (long long)res * res != (long long)out_size ||
        ws_size < cnt_bytes + rec_bytes) {
        tp_direct<<<(n + 255) / 256, 256, 0, stream>>>(
            pos, velv, rot, obs, rc, dw, t, maxd, box, shell, ridx, out, res, n);
        return;
    }

    unsigned* gcnt = (unsigned*)d_ws;
    unsigned* grec = (unsigned*)((char*)d_ws + cnt_bytes);

    hipMemsetAsync(gcnt, 0, cnt_bytes, stream);

    const int per_round = NBLK * NTH * VEC;
    const int rounds = (n + per_round - 1) / per_round;
    tp_bin<<<NBLK, NTH, 0, stream>>>(
        pos, velv, rot, obs, rc, dw, t, maxd, box, shell, ridx,
        gcnt, grec, out, res, tiles, n, rounds);

    tp_paint<<<nt2, 1024, 0, stream>>>(gcnt, grec, out, res, tiles);
}

// Round 8
// 280.758 us; speedup vs baseline: 1.2279x; 1.0108x over previous
//
#include <hip/hip_runtime.h>
#include <cmath>

// TelephotoInterp: rotate+shift+drift 8.4M particles, CIC-paint z-slab onto
// res x res (2048^2) f32 grid.
//
// Round-14: r7 proved the iteration is a ~2 TB/s BYTE pipeline: tp_bin
// -22us (nt loads, 89->67) left total unchanged; r6's +174MB cost +63us.
// Per-dispatch rocprof durations are serialized-replay artifacts; only
// bytes matter. Byte diet this round: eliminate paint's interior += READ
// of out (16.8 MB) -- it existed only to merge bin's rare scatter_direct
// overflow atomics. Overflow now goes to a global side-list (bucket,rec)
// that paint folds into its LDS quad; interior cells become exclusively
// paint-owned -> "=" write-only. Flag preserves correctness if the list
// ever fills (device-wide fallback to +=). CAP 4096->4016 carves the
// 524KB list from the proven 33.56MB ws budget. Bin = r7 verbatim
// (nt float4 loads, LDS-batched flush).

#define TSZ    128        // paint tile edge (cells)
#define NBKT   256        // K1 buckets (= max tiles^2 in fast path, tiles<=16)
#define NXCC   8
#define CAP    4016       // records per (xcc,bucket) segment (mean ~2050)
#define DEPTH  32         // LDS slots per bucket
#define NTH    256        // K1 block size
#define NBLK   1024       // K1 grid (4 blocks/CU, persistent)
#define VEC    4          // particles per thread per round
#define DESCMAX 512       // sum floor(c/16) <= NBKT*DEPTH/16 = 512
#define OVFMAX 65536      // side-list capacity (expected load ~1e3)

typedef float vf4 __attribute__((ext_vector_type(4)));

__device__ __forceinline__ int get_xcc_id() {
    // s_getreg_b32 hwreg(HW_REG_XCC_ID=20, offset=0, size=4)  [learn_hip m09]
    int x = __builtin_amdgcn_s_getreg((3 << 11) | (0 << 6) | 20);
    return x & (NXCC - 1);   // any value in [0,8) is CORRECT; only perf differs
}

__device__ __forceinline__ float fast_rcp(float x)  { return __builtin_amdgcn_rcpf(x); }
__device__ __forceinline__ float fast_sqrt(float x) { return __builtin_amdgcn_sqrtf(x); }

__device__ __forceinline__ int wrap_idx(int v, int res) {   // generic (fallback path)
    v += (v < 0) ? res : 0;
    v += (v < 0) ? res : 0;
    v += (v < 0) ? res : 0;
    v -= (v >= res) ? res : 0;
    v -= (v >= res) ? res : 0;
    v -= (v >= res) ? res : 0;
    if (v < 0 || v >= res) { v %= res; if (v < 0) v += res; }  // safety net
    return v;
}

__device__ __forceinline__ void scatter_direct(float* __restrict__ out, int res,
                                               int gx0, int gy0, float fx, float fy) {
    int gx1 = gx0 + 1; if (gx1 >= res) gx1 = 0;
    int gy1 = gy0 + 1; if (gy1 >= res) gy1 = 0;
    atomicAdd(&out[gx0 * res + gy0], (1.0f - fx) * (1.0f - fy));
    atomicAdd(&out[gx1 * res + gy0], fx * (1.0f - fy));
    atomicAdd(&out[gx0 * res + gy1], (1.0f - fx) * fy);
    atomicAdd(&out[gx1 * res + gy1], fx * fy);
}

// rec = lx7<<25 | ly7<<18 | qx9<<9 | qy9
__device__ __forceinline__ void rec_decode(unsigned rec, int b, int tiles,
                                           int& gx, int& gy, float& fx, float& fy) {
    int tx = b / tiles, ty = b - tx * tiles;   // rare path only
    gx = (tx << 7) + (int)(rec >> 25);
    gy = (ty << 7) + (int)((rec >> 18) & 127u);
    fx = (float)((rec >> 9) & 511u) * (1.0f / 512.0f);
    fy = (float)(rec & 511u) * (1.0f / 512.0f);
}

// uniforms for the per-particle fast path
struct Uni {
    float m00, m01, m02, m10, m11, m12, m20, m21, m22;
    float ox, oy, oz, shift;
    float r_lo, r_hi, t, gp_t, scale;
    int   resm1, res, tiles;
    bool  inside;
};

// ---------------- K1 per-particle fast path ----------------
__device__ __forceinline__ void tp_process(
    const Uni& u, float px, float py, float pz, float vx, float vy, float vz,
    unsigned* __restrict__ fill, unsigned* __restrict__ buf,
    unsigned* __restrict__ ovfcnt, unsigned long long* __restrict__ ovf,
    float* __restrict__ out)
{
    float X, Y, Z;
    if (u.inside) {
        X = px; Y = py; Z = pz;
    } else {
        const float qx_ = px - u.ox, qy_ = py - u.oy, qz_ = pz - u.oz;
        float rx = u.m00 * qx_ + u.m01 * qy_ + u.m02 * qz_;
        float ry = u.m10 * qx_ + u.m11 * qy_ + u.m12 * qz_;
        float rz = u.m20 * qx_ + u.m21 * qy_ + u.m22 * qz_ + u.shift;

        const float vrx = u.m00 * vx + u.m01 * vy + u.m02 * vz;
        const float vry = u.m10 * vx + u.m11 * vy + u.m12 * vz;
        const float vrz = u.m20 * vx + u.m21 * vy + u.m22 * vz;

        const float dx = rx - u.ox, dy = ry - u.oy, dz = rz - u.oz;
        const float dist  = fast_sqrt(dx * dx + dy * dy + dz * dz);
        const float a_tgt = fast_rcp(1.0f + dist * (1.0f / 3000.0f));
        const float ac    = fast_sqrt(u.t * a_tgt);
        const float gp_a  = a_tgt * fast_sqrt(a_tgt);          // a^1.5
        const float drift = (gp_a - u.gp_t) * fast_rcp(1.5f * fast_sqrt(ac));

        X = rx + drift * vrx + u.ox;
        Y = ry + drift * vry + u.oy;
        Z = rz + drift * vrz + u.oz;
    }
    if (!(Z >= u.r_lo && Z < u.r_hi)) return;

    const float gx = X * u.scale, gy = Y * u.scale;
    const float fgx = floorf(gx), fgy = floorf(gy);
    const float fx = gx - fgx, fy = gy - fgy;
    const int ix0 = ((int)fgx) & u.resm1;   // exact mod for pow2 res
    const int iy0 = ((int)fgy) & u.resm1;
    const int st = (ix0 >> 7) * u.tiles + (iy0 >> 7);

    unsigned qx = (unsigned)(fx * 512.0f + 0.5f); if (qx > 511u) qx = 511u;
    unsigned qy = (unsigned)(fy * 512.0f + 0.5f); if (qy > 511u) qy = 511u;
    const unsigned rec = ((unsigned)(ix0 & 127) << 25) | ((unsigned)(iy0 & 127) << 18)
                       | (qx << 9) | qy;

    unsigned p = atomicAdd(&fill[st], 1u);
    if (p < DEPTH) buf[st * DEPTH + p] = rec;
    else {
        atomicSub(&fill[st], 1u);
        const unsigned idx = atomicAdd(ovfcnt, 1u);
        if (idx < OVFMAX) ovf[idx] = ((unsigned long long)(unsigned)st << 32) | rec;
        else scatter_direct(out, u.res, ix0, iy0, fx, fy);   // last resort (flagged)
    }
}

// ---------------- K1: transform + LDS-batched bin ----------------
__global__ __launch_bounds__(NTH) void tp_bin(
    const float* __restrict__ pos, const float* __restrict__ vel,
    const float* __restrict__ rotations, const float* __restrict__ observer,
    const float* __restrict__ r_centers, const float* __restrict__ widths,
    const float* __restrict__ t_p, const float* __restrict__ maxd_p,
    const float* __restrict__ box_p, const int* __restrict__ shell_p,
    const int* __restrict__ ridx_p,
    unsigned* __restrict__ gcnt, unsigned* __restrict__ grec,
    unsigned* __restrict__ ovfcnt, unsigned long long* __restrict__ ovf,
    float* __restrict__ out, int res, int tiles, int n, int rounds)
{
    __shared__ unsigned fill[NBKT];
    __shared__ unsigned buf[NBKT * DEPTH];
    __shared__ unsigned descB[DESCMAX];
    __shared__ unsigned descD[DESCMAX];
    __shared__ unsigned ndesc;

    const int tid = threadIdx.x;
    for (int b = tid; b < NBKT; b += NTH) fill[b] = 0;
    if (tid == 0) ndesc = 0;

    Uni u;
    {
        const int   shell    = shell_p[0];
        const float r_center = r_centers[shell];
        const float width    = widths[shell];
        const float maxd     = maxd_p[0];
        const float box      = box_p[0];
        u.t      = t_p[0];
        u.inside = (r_center + width * 0.5f) <= maxd;
        int ridx = ridx_p[0] % 47; if (ridx < 0) ridx += 47;
        const float* M = rotations + 9 * ridx;
        u.m00 = M[0]; u.m01 = M[1]; u.m02 = M[2];
        u.m10 = M[3]; u.m11 = M[4]; u.m12 = M[5];
        u.m20 = M[6]; u.m21 = M[7]; u.m22 = M[8];
        u.ox = observer[0]; u.oy = observer[1]; u.oz = observer[2];
        u.shift = floorf(r_center / maxd) * maxd;
        u.r_lo = r_center - width * 0.5f;
        u.r_hi = r_center + width * 0.5f;
        u.gp_t = u.t * sqrtf(u.t);
        u.scale = (float)res / box;
        u.resm1 = res - 1; u.res = res; u.tiles = tiles;
    }

    const int xcc = get_xcc_id();
    const int segbase = xcc * NBKT;
    const vf4* __restrict__ pos4 = (const vf4*)pos;
    const vf4* __restrict__ vel4 = (const vf4*)vel;

    __syncthreads();

    for (int r = 0; r < rounds; ++r) {
        const int base = ((r * NBLK + blockIdx.x) * NTH + tid) * VEC;
        // phase 1: transform + deposit (4 particles via 3+3 float4 nt-loads)
        if (base + VEC <= n) {
            const int q = base * 3 / 4;   // float4 index (base*3 divisible by 4)
            const vf4 a = __builtin_nontemporal_load(pos4 + q);
            const vf4 b = __builtin_nontemporal_load(pos4 + q + 1);
            const vf4 c = __builtin_nontemporal_load(pos4 + q + 2);
            if (u.inside) {
                tp_process(u, a.x, a.y, a.z, 0, 0, 0, fill, buf, ovfcnt, ovf, out);
                tp_process(u, a.w, b.x, b.y, 0, 0, 0, fill, buf, ovfcnt, ovf, out);
                tp_process(u, b.z, b.w, c.x, 0, 0, 0, fill, buf, ovfcnt, ovf, out);
                tp_process(u, c.y, c.z, c.w, 0, 0, 0, fill, buf, ovfcnt, ovf, out);
            } else {
                const vf4 d = __builtin_nontemporal_load(vel4 + q);
                const vf4 e = __builtin_nontemporal_load(vel4 + q + 1);
                const vf4 f = __builtin_nontemporal_load(vel4 + q + 2);
                tp_process(u, a.x, a.y, a.z, d.x, d.y, d.z, fill, buf, ovfcnt, ovf, out);
                tp_process(u, a.w, b.x, b.y, d.w, e.x, e.y, fill, buf, ovfcnt, ovf, out);
                tp_process(u, b.z, b.w, c.x, e.z, e.w, f.x, fill, buf, ovfcnt, ovf, out);
                tp_process(u, c.y, c.z, c.w, f.y, f.z, f.w, fill, buf, ovfcnt, ovf, out);
            }
        } else {
            for (int p = 0; p < VEC; ++p) {
                const int i = base + p;
                if (i < n)
                    tp_process(u, pos[3 * i], pos[3 * i + 1], pos[3 * i + 2],
                               vel[3 * i], vel[3 * i + 1], vel[3 * i + 2],
                               fill, buf, ovfcnt, ovf, out);
            }
        }
        __syncthreads();
        // phase 2a: build flush descriptors (thread b <-> bucket b)
        if (tid < NBKT) {
            const unsigned c = fill[tid];
            const unsigned k = c >> 4;
            if (k) {
                unsigned gbase = atomicAdd(&gcnt[segbase + tid], 16u * k);
                unsigned d = atomicAdd(&ndesc, k);
                for (unsigned g = 0; g < k; ++g) {
                    descB[d + g] = (unsigned)tid | ((g * 16u) << 16);
                    descD[d + g] = gbase + 16u * g;
                }
            }
        }
        __syncthreads();
        // phase 2b: cooperative coalesced flush, 16 lanes per descriptor
        const unsigned nd = ndesc;
        for (unsigned did = (unsigned)(tid >> 4); did < nd; did += NTH / 16) {
            const unsigned e = descB[did];
            const unsigned b = e & 0xffffu, so = e >> 16;
            const unsigned dst = descD[did] + (unsigned)(tid & 15);
            const unsigned rv = buf[b * DEPTH + so + (tid & 15)];
            if (dst < CAP) {
                grec[(size_t)(segbase + b) * CAP + dst] = rv;
            } else {  // segment overflow -> side-list (exact same record)
                const unsigned idx = atomicAdd(ovfcnt, 1u);
                if (idx < OVFMAX) ovf[idx] = ((unsigned long long)b << 32) | rv;
                else {
                    int gx0, gy0; float ffx, ffy;
                    rec_decode(rv, (int)b, u.tiles, gx0, gy0, ffx, ffy);
                    scatter_direct(out, u.res, gx0, gy0, ffx, ffy);
                }
            }
        }
        __syncthreads();
        // phase 2c: compact residues, reset descriptor count
        if (tid < NBKT) {
            const unsigned c = fill[tid];
            const unsigned k = c >> 4;
            if (k) {
                const unsigned resid = c - 16u * k;
                for (unsigned j = 0; j < resid; ++j)
                    buf[tid * DEPTH + j] = buf[tid * DEPTH + 16u * k + j];
                fill[tid] = resid;
            }
        }
        if (tid == 0) ndesc = 0;
        __syncthreads();
    }

    // final flush: drain residues (c <= 15 each)
    if (tid < NBKT) {
        const unsigned c = fill[tid];
        if (c) {
            unsigned d = atomicAdd(&ndesc, 1u);
            unsigned gbase = atomicAdd(&gcnt[segbase + tid], c);
            descB[d] = (unsigned)tid | (c << 16);
            descD[d] = gbase;
        }
    }
    __syncthreads();
    const unsigned nd = ndesc;
    for (unsigned did = (unsigned)(tid >> 4); did < nd; did += NTH / 16) {
        const unsigned e = descB[did];
        const unsigned b = e & 0xffffu, c = e >> 16;
        const unsigned lane = (unsigned)(tid & 15);
        if (lane < c) {
            const unsigned dst = descD[did] + lane;
            const unsigned rv = buf[b * DEPTH + lane];
            if (dst < CAP) {
                grec[(size_t)(segbase + b) * CAP + dst] = rv;
            } else {
                const unsigned idx = atomicAdd(ovfcnt, 1u);
                if (idx < OVFMAX) ovf[idx] = ((unsigned long long)b << 32) | rv;
                else {
                    int gx0, gy0; float ffx, ffy;
                    rec_decode(rv, (int)b, u.tiles, gx0, gy0, ffx, ffy);
                    scatter_direct(out, u.res, gx0, gy0, ffx, ffy);
                }
            }
        }
    }
}

// ---------------- K2: paint (one 128-tile per block, quad u64 accumulate) ----
// 4 parity-staggered quad grids; a record at (li,lj) hits exactly one quad:
// grid (li&1, lj&1), index (li>>1, lj>>1). u64 = 4x u16 fixed-point (2^-10):
// slot(r,s) at bits 16*(r*2+s) = weight for cell (li+r, lj+s). Exact while
// each cell's weight-sum < 64 (actual max ~12).
// Side-list entries for this bucket are folded into quad too, so interior
// cells are exclusively paint-owned -> "=" (write-only, no += read). If the
// side-list overflowed (flag), bin used out-atomics -> fall back to +=.
__global__ __launch_bounds__(1024) void tp_paint(
    const unsigned* __restrict__ gcnt, const unsigned* __restrict__ grec,
    const unsigned* __restrict__ ovfcnt, const unsigned long long* __restrict__ ovf,
    float* __restrict__ out, int res, int tiles)
{
    __shared__ unsigned long long quad[4][64 * 64];   // 128 KB
    const int b = blockIdx.x;
    const int tx = b / tiles, ty = b - tx * tiles;

    for (int c = threadIdx.x; c < 4 * 64 * 64; c += blockDim.x)
        quad[c >> 12][c & 4095] = 0ull;
    __syncthreads();

    for (int x = 0; x < NXCC; ++x) {
        unsigned m = gcnt[x * NBKT + b]; if (m > CAP) m = CAP;
        const unsigned* rr = grec + (size_t)(x * NBKT + b) * CAP;
        for (unsigned k = threadIdx.x; k < m; k += blockDim.x) {
            const unsigned p = rr[k];
            const int li = (int)(p >> 25);
            const int lj = (int)((p >> 18) & 127u);
            const unsigned qx = (p >> 9) & 511u;
            const unsigned qy = p & 511u;
            const unsigned ax = 512u - qx, ay = 512u - qy;
            const unsigned long long w00 = (ax * ay + 128u) >> 8;
            const unsigned long long w01 = (ax * qy + 128u) >> 8;
            const unsigned long long w10 = (qx * ay + 128u) >> 8;
            const unsigned long long w11 = (qx * qy + 128u) >> 8;
            const unsigned long long pk = w00 | (w01 << 16) | (w10 << 32) | (w11 << 48);
            const int g = ((li & 1) << 1) | (lj & 1);
            atomicAdd(&quad[g][(li >> 1) * 64 + (lj >> 1)], pk);
        }
    }

    // fold side-list records belonging to this bucket (list is tiny & hot)
    const unsigned ovfn_raw = ovfcnt[0];
    const bool accum = ovfn_raw > OVFMAX;   // last-resort atomics were used
    const unsigned ovfn = accum ? (unsigned)OVFMAX : ovfn_raw;
    for (unsigned k = threadIdx.x; k < ovfn; k += blockDim.x) {
        const unsigned long long e = ovf[k];
        if ((unsigned)(e >> 32) == (unsigned)b) {
            const unsigned p = (unsigned)e;
            const int li = (int)(p >> 25);
            const int lj = (int)((p >> 18) & 127u);
            const unsigned qx = (p >> 9) & 511u;
            const unsigned qy = p & 511u;
            const unsigned ax = 512u - qx, ay = 512u - qy;
            const unsigned long long w00 = (ax * ay + 128u) >> 8;
            const unsigned long long w01 = (ax * qy + 128u) >> 8;
            const unsigned long long w10 = (qx * ay + 128u) >> 8;
            const unsigned long long w11 = (qx * qy + 128u) >> 8;
            const unsigned long long pk = w00 | (w01 << 16) | (w10 << 32) | (w11 << 48);
            const int g = ((li & 1) << 1) | (lj & 1);
            atomicAdd(&quad[g][(li >> 1) * 64 + (lj >> 1)], pk);
        }
    }
    __syncthreads();

    for (int c = threadIdx.x; c < (TSZ + 1) * (TSZ + 1); c += blockDim.x) {
        const int i = c / (TSZ + 1), j = c - i * (TSZ + 1);
        unsigned acc = 0;
        #pragma unroll
        for (int r = 0; r < 2; ++r) {
            const int ii = i - r;
            if (ii < 0 || ii > TSZ - 1) continue;
            #pragma unroll
            for (int s = 0; s < 2; ++s) {
                const int jj = j - s;
                if (jj < 0 || jj > TSZ - 1) continue;
                const int g = ((ii & 1) << 1) | (jj & 1);
                const unsigned long long v = quad[g][(ii >> 1) * 64 + (jj >> 1)];
                acc += (unsigned)((v >> (16 * (r * 2 + s))) & 0xffffull);
            }
        }
        const float val = (float)acc * (1.0f / 1024.0f);
        int gx = tx * TSZ + i; if (gx >= res) gx -= res;
        int gy = ty * TSZ + j; if (gy >= res) gy -= res;
        float* dst = &out[gx * res + gy];
        if (i == 0 || j == 0 || i == TSZ || j == TSZ) {
            if (val != 0.0f) atomicAdd(dst, val);   // halo-shared frame cells
        } else if (accum) {
            *dst += val;   // rare: merge with last-resort out-atomics
        } else {
            *dst = val;    // exclusive writer, write-only (no read)
        }
    }
}

// ---------------- fallback direct kernel (non-pow2 / odd res / small ws) ----
__global__ __launch_bounds__(256) void tp_direct(
    const float* __restrict__ pos, const float* __restrict__ vel,
    const float* __restrict__ rotations, const float* __restrict__ observer,
    const float* __restrict__ r_centers, const float* __restrict__ widths,
    const float* __restrict__ t_p, const float* __restrict__ maxd_p,
    const float* __restrict__ box_p, const int* __restrict__ shell_p,
    const int* __restrict__ ridx_p, float* __restrict__ out, int res, int n)
{
    int i = blockIdx.x * blockDim.x + threadIdx.x;
    if (i >= n) return;
    const int   shell    = shell_p[0];
    const float r_center = r_centers[shell];
    const float width    = widths[shell];
    const float maxd     = maxd_p[0];
    const float box      = box_p[0];
    const float t        = t_p[0];
    const bool  inside   = (r_center + width * 0.5f) <= maxd;
    int ridx = ridx_p[0] % 47; if (ridx < 0) ridx += 47;

    float px = pos[3 * i], py = pos[3 * i + 1], pz = pos[3 * i + 2];
    float X, Y, Z;
    if (inside) {
        X = px; Y = py; Z = pz;
    } else {
        const float* M = rotations + 9 * ridx;
        const float ox = observer[0], oy = observer[1], oz = observer[2];
        const float qx = px - ox, qy = py - oy, qz = pz - oz;
        float rx = M[0] * qx + M[1] * qy + M[2] * qz;
        float ry = M[3] * qx + M[4] * qy + M[5] * qz;
        float rz = M[6] * qx + M[7] * qy + M[8] * qz + floorf(r_center / maxd) * maxd;
        const float vx = vel[3 * i], vy = vel[3 * i + 1], vz = vel[3 * i + 2];
        const float vrx = M[0] * vx + M[1] * vy + M[2] * vz;
        const float vry = M[3] * vx + M[4] * vy + M[5] * vz;
        const float vrz = M[6] * vx + M[7] * vy + M[8] * vz;
        const float dx = rx - ox, dy = ry - oy, dz = rz - oz;
        const float dist  = sqrtf(dx * dx + dy * dy + dz * dz);
        const float a_tgt = 1.0f / (1.0f + dist / 3000.0f);
        const float ac    = sqrtf(t * a_tgt);
        const float drift = (a_tgt * sqrtf(a_tgt) - t * sqrtf(t)) / (1.5f * sqrtf(ac));
        X = rx + drift * vrx + ox;
        Y = ry + drift * vry + oy;
        Z = rz + drift * vrz + oz;
    }
    if (!(Z >= r_center - width * 0.5f && Z < r_center + width * 0.5f)) return;

    const float scale = (float)res / box;
    const float gx = X * scale, gy = Y * scale;
    const float fgx = floorf(gx), fgy = floorf(gy);
    scatter_direct(out, res, wrap_idx((int)fgx, res), wrap_idx((int)fgy, res),
                   gx - fgx, gy - fgy);
}

extern "C" void kernel_launch(void* const* d_in, const int* in_sizes, int n_in,
                              void* d_out, int out_size, void* d_ws, size_t ws_size,
                              hipStream_t stream) {
    const float* pos   = (const float*)d_in[0];
    const float* velv  = (const float*)d_in[1];
    const float* rot   = (const float*)d_in[2];
    const float* obs   = (const float*)d_in[3];
    const float* rc    = (const float*)d_in[4];
    const float* dw    = (const float*)d_in[5];
    const float* t     = (const float*)d_in[6];
    const float* maxd  = (const float*)d_in[7];
    const float* box   = (const float*)d_in[8];
    const int*   shell = (const int*)d_in[9];
    const int*   ridx  = (const int*)d_in[10];
    float* out = (float*)d_out;

    const int n   = in_sizes[0] / 3;
    const int res = (int)llround(sqrt((double)out_size));

    // output is poisoned with 0xAA before every timed launch — zero it.
    hipMemsetAsync(out, 0, (size_t)out_size * sizeof(float), stream);

    const int tiles = res / TSZ;
    const int nt2 = tiles * tiles;
    const size_t cnt_bytes = (size_t)NXCC * NBKT * sizeof(unsigned);   // 8 KB
    const size_t ovf_bytes = 16 + (size_t)OVFMAX * 8;                  // cnt+list
    const size_t rec_bytes = (size_t)NXCC * NBKT * CAP * sizeof(unsigned);
    const bool pow2 = res > 0 && (res & (res - 1)) == 0;

    if (!pow2 || res % TSZ != 0 || nt2 > NBKT ||
        (long long)res * res != (long long)out_size ||
        ws_size < cnt_bytes + ovf_bytes + rec_bytes) {
        tp_direct<<<(n + 255) / 256, 256, 0, stream>>>(
            pos, velv, rot, obs, rc, dw, t, maxd, box, shell, ridx, out, res, n);
        return;
    }

    unsigned* gcnt = (unsigned*)d_ws;
    unsigned* ovfcnt = (unsigned*)((char*)d_ws + cnt_bytes);
    unsigned long long* ovf = (unsigned long long*)((char*)d_ws + cnt_bytes + 16);
    unsigned* grec = (unsigned*)((char*)d_ws + cnt_bytes + ovf_bytes);

    hipMemsetAsync(gcnt, 0, cnt_bytes + 16, stream);   // zeros gcnt + ovfcnt

    const int per_round = NBLK * NTH * VEC;
    const int rounds = (n + per_round - 1) / per_round;
    tp_bin<<<NBLK, NTH, 0, stream>>>(
        pos, velv, rot, obs, rc, dw, t, maxd, box, shell, ridx,
        gcnt, grec, ovfcnt, ovf, out, res, tiles, n, rounds);

    tp_paint<<<nt2, 1024, 0, stream>>>(gcnt, grec, ovfcnt, ovf, out, res, tiles);
}